// Round 3
// baseline (46968.646 us; speedup 1.0000x reference)
//
#include <hip/hip_runtime.h>
#include <math.h>

// CustomGRU B=64,S=512,F=512,H=1024. FP32 I/O, split-bf16 (hi+lo) MFMA compute.
// Round 2: ONE persistent cooperative kernel for all 512 timesteps.
//   - Wp[4j+g][k] gate-interleaved packed weights, zero-padded K=1536 so all
//     4 gates are one uniform GEMM. wg w owns cols 4w..4w+3 (16 packed rows),
//     stages its 98.8 KB hi+lo slice into LDS once (stride 1544: 2-way bank
//     aliasing = free).
//   - Per step: 8 waves split K 8x192; each wave: 4 batch-tiles x 16 cols,
//     MFMA3 split (hi*HI+hi*LO+lo*HI); partials via LDS; 256 epilogue threads
//     do gates + h update (fp32 + double-buffered bf16 hi/lo) + out write.
//   - Grid barrier: ticket counter, device-scope atomics, monotone target.

#define B_   64
#define S_   512
#define F_   512
#define H_   1024
#define KTOT 1536
#define NG   4096
#define NWG  256
#define NTHR 512
#define KCH  192              // K per wave
#define RS   1544             // padded LDS row stride (shorts)
#define SMEM_BYTES (2 * 16 * RS * 2 + 32 * 256 * 4)   // 98816 + 32768 = 131584

typedef short short8 __attribute__((ext_vector_type(8)));
typedef float floatx4 __attribute__((ext_vector_type(4)));

__device__ __forceinline__ float bf2f(unsigned short u) {
    union { unsigned int i; float f; } v; v.i = ((unsigned int)u) << 16; return v.f;
}
__device__ __forceinline__ unsigned short f2bf(float f) {
    union { float f; unsigned int i; } v; v.f = f;
    unsigned int x = v.i;
    x += 0x7fffu + ((x >> 16) & 1u);
    return (unsigned short)(x >> 16);
}
__device__ __forceinline__ void split2(float v, unsigned short& hi, unsigned short& lo) {
    hi = f2bf(v);
    lo = f2bf(v - bf2f(hi));
}

__global__ void pack_w(const float* __restrict__ Wih,
                       const float* __restrict__ Whh,
                       unsigned short* __restrict__ Whi,
                       unsigned short* __restrict__ Wlo) {
    int idx = blockIdx.x * 256 + threadIdx.x;   // < NG*KTOT
    int p = idx / KTOT;
    int k = idx - p * KTOT;
    int j = p >> 2, g = p & 3;
    float v = 0.f;
    if (g == 0)      v = (k < F_) ? Wih[k * 3072 + j]        : Whh[(k - F_) * 3072 + j];
    else if (g == 1) v = (k < F_) ? Wih[k * 3072 + 1024 + j] : Whh[(k - F_) * 3072 + 1024 + j];
    else if (g == 2) { if (k <  F_) v = Wih[k * 3072 + 2048 + j]; }
    else             { if (k >= F_) v = Whh[(k - F_) * 3072 + 2048 + j]; }
    unsigned short hi, lo; split2(v, hi, lo);
    Whi[idx] = hi; Wlo[idx] = lo;
}

__global__ void pack_x(const float* __restrict__ x,
                       unsigned short* __restrict__ xhi,
                       unsigned short* __restrict__ xlo) {
    int idx = blockIdx.x * 256 + threadIdx.x;   // < B_*S_*F_
    unsigned short hi, lo; split2(x[idx], hi, lo);
    xhi[idx] = hi; xlo[idx] = lo;
}

__device__ __forceinline__ void ks_step(floatx4* acc,
    const unsigned short* __restrict__ Ahi, const unsigned short* __restrict__ Alo,
    size_t aofs, size_t astride,
    const unsigned short* Bh_, const unsigned short* Bl_, int bofs)
{
    short8 bh = *(const short8*)&Bh_[bofs];
    short8 bl = *(const short8*)&Bl_[bofs];
    #pragma unroll
    for (int mt = 0; mt < 4; ++mt) {
        size_t o = aofs + (size_t)mt * astride;
        short8 ah = *(const short8*)&Ahi[o];
        short8 al = *(const short8*)&Alo[o];
        acc[mt] = __builtin_amdgcn_mfma_f32_16x16x32_bf16(ah, bh, acc[mt], 0, 0, 0);
        acc[mt] = __builtin_amdgcn_mfma_f32_16x16x32_bf16(ah, bl, acc[mt], 0, 0, 0);
        acc[mt] = __builtin_amdgcn_mfma_f32_16x16x32_bf16(al, bh, acc[mt], 0, 0, 0);
    }
}

__global__ __launch_bounds__(NTHR) void gru_persist(
    const unsigned short* __restrict__ xhi,
    const unsigned short* __restrict__ xlo,
    const unsigned short* __restrict__ Whi,
    const unsigned short* __restrict__ Wlo,
    const float* __restrict__ bias,
    float* __restrict__ hf,
    unsigned short* hhi0, unsigned short* hlo0,
    unsigned short* hhi1, unsigned short* hlo1,
    float* __restrict__ out,
    float* __restrict__ hlast,
    unsigned* bar)
{
    extern __shared__ char smem[];
    unsigned short* Bh = (unsigned short*)smem;                 // 16 x RS shorts
    unsigned short* Bl = Bh + 16 * RS;
    float* Cp = (float*)(smem + 2 * 16 * RS * 2);               // 32 tiles x 256 f32

    const int tid = threadIdx.x;
    const int wg  = blockIdx.x;

    // ---- stage this wg's weight slice into LDS (once) ----
    for (int c = tid; c < 16 * 192; c += NTHR) {
        int row = c / 192, c8 = c - row * 192;
        size_t gofs = (size_t)(wg * 16 + row) * KTOT + c8 * 8;
        *(short8*)&Bh[row * RS + c8 * 8] = *(const short8*)&Whi[gofs];
        *(short8*)&Bl[row * RS + c8 * 8] = *(const short8*)&Wlo[gofs];
    }
    __syncthreads();

    const int lane = tid & 63;
    const int kw   = tid >> 6;                 // wave id 0..7 -> K chunk
    const int l15  = lane & 15, quad = lane >> 4;
    const int kbase = kw * KCH;
    const int bofs  = l15 * RS + kbase + quad * 8;

    // epilogue constants (threads 0..255: one (batch, col) pair each)
    const int eb   = tid & 63;
    const int ejj  = (tid >> 6) & 3;
    const int ecol = wg * 4 + ejj;
    float bZ = 0.f, bR = 0.f, bE = 0.f;
    if (tid < 256) {
        bZ = bias[ecol];
        bR = bias[H_ + ecol];
        bE = bias[2 * H_ + ecol];
    }
    const int emt = eb >> 4, erow = eb & 15;
    const int elb = (erow >> 2) * 16, err = erow & 3;
    const int ehidx = eb * H_ + ecol;

    const size_t XMT = (size_t)16 * S_ * F_;   // batch-tile stride in x
    const size_t HMT = (size_t)16 * H_;        // batch-tile stride in h
    const size_t hrow = (size_t)l15 * H_ + quad * 8;

    for (int t = 0; t < S_; ++t) {
        const unsigned short* hih = (t & 1) ? hhi1 : hhi0;
        const unsigned short* hil = (t & 1) ? hlo1 : hlo0;
        unsigned short* hoh = (t & 1) ? hhi0 : hhi1;
        unsigned short* hol = (t & 1) ? hlo0 : hlo1;

        floatx4 z4 = {0.f, 0.f, 0.f, 0.f};
        floatx4 acc[4] = {z4, z4, z4, z4};

        const size_t xrow = ((size_t)l15 * S_ + t) * F_ + quad * 8;

        if (kbase + KCH <= 512) {              // waves 0,1: pure x
            #pragma unroll
            for (int ks = 0; ks < 6; ++ks)
                ks_step(acc, xhi, xlo, xrow + kbase + ks * 32, XMT, Bh, Bl, bofs + ks * 32);
        } else if (kbase >= 512) {             // waves 3..7: pure h
            #pragma unroll
            for (int ks = 0; ks < 6; ++ks)
                ks_step(acc, hih, hil, hrow + (kbase - 512) + ks * 32, HMT, Bh, Bl, bofs + ks * 32);
        } else {                               // wave 2: 4 x-steps + 2 h-steps
            #pragma unroll
            for (int ks = 0; ks < 4; ++ks)
                ks_step(acc, xhi, xlo, xrow + kbase + ks * 32, XMT, Bh, Bl, bofs + ks * 32);
            #pragma unroll
            for (int ks = 4; ks < 6; ++ks)
                ks_step(acc, hih, hil, hrow + (kbase - 512) + ks * 32, HMT, Bh, Bl, bofs + ks * 32);
        }

        #pragma unroll
        for (int mt = 0; mt < 4; ++mt)
            *(floatx4*)&Cp[((kw * 4 + mt) << 8) + lane * 4] = acc[mt];
        __syncthreads();

        if (tid < 256) {
            float g[4];
            #pragma unroll
            for (int gi = 0; gi < 4; ++gi) {
                const int c = ejj * 4 + gi;
                const int base = (elb + c) * 4 + err;
                float s = 0.f;
                #pragma unroll
                for (int k2 = 0; k2 < 8; ++k2)
                    s += Cp[((k2 * 4 + emt) << 8) + base];
                g[gi] = s;
            }
            float z   = 1.f / (1.f + __expf(-(g[0] + bZ)));
            float rr  = 1.f / (1.f + __expf(-(g[1] + bR)));
            float eta = tanhf(g[2] + bE + rr * tanhf(g[3]));
            float ho  = hf[ehidx];
            float hn  = z * ho + (1.f - z) * eta;
            hf[ehidx] = hn;
            unsigned short hi, lo; split2(hn, hi, lo);
            hoh[ehidx] = hi;
            hol[ehidx] = lo;
            out[((size_t)eb * S_ + t) * H_ + ecol] = hn;
            if (t == S_ - 1) hlast[ehidx] = hn;
        }

        // ---- grid barrier (ticket, monotone target, device scope) ----
        __threadfence();
        __syncthreads();
        if (tid == 0) {
            __hip_atomic_fetch_add(bar, 1u, __ATOMIC_RELEASE, __HIP_MEMORY_SCOPE_AGENT);
            const unsigned target = (unsigned)(t + 1) * NWG;
            while (__hip_atomic_load(bar, __ATOMIC_ACQUIRE, __HIP_MEMORY_SCOPE_AGENT) < target)
                __builtin_amdgcn_s_sleep(2);
            __threadfence();
        }
        __syncthreads();
    }
}

extern "C" void kernel_launch(void* const* d_in, const int* in_sizes, int n_in,
                              void* d_out, int out_size, void* d_ws, size_t ws_size,
                              hipStream_t stream) {
    const float* x    = (const float*)d_in[0];   // [B,S,F]
    const float* Wih  = (const float*)d_in[1];   // [F,3H]
    const float* Whh  = (const float*)d_in[2];   // [H,3H]
    const float* bias = (const float*)d_in[3];   // [3H]
    float* out = (float*)d_out;                  // [B,S,H] ++ [B,H]

    char* ws = (char*)d_ws;
    unsigned short* Whi = (unsigned short*)ws; ws += (size_t)NG * KTOT * 2;
    unsigned short* Wlo = (unsigned short*)ws; ws += (size_t)NG * KTOT * 2;
    unsigned short* xhi = (unsigned short*)ws; ws += (size_t)B_ * S_ * F_ * 2;
    unsigned short* xlo = (unsigned short*)ws; ws += (size_t)B_ * S_ * F_ * 2;
    float* hf = (float*)ws;                    ws += (size_t)B_ * H_ * 4;
    unsigned short* hhi0 = (unsigned short*)ws; ws += (size_t)B_ * H_ * 2;
    unsigned short* hlo0 = (unsigned short*)ws; ws += (size_t)B_ * H_ * 2;
    unsigned short* hhi1 = (unsigned short*)ws; ws += (size_t)B_ * H_ * 2;
    unsigned short* hlo1 = (unsigned short*)ws; ws += (size_t)B_ * H_ * 2;
    unsigned* bar = (unsigned*)ws;             ws += 64;

    hipMemsetAsync(hf,   0, (size_t)B_ * H_ * 4, stream);
    hipMemsetAsync(hhi0, 0, (size_t)B_ * H_ * 2, stream);
    hipMemsetAsync(hlo0, 0, (size_t)B_ * H_ * 2, stream);
    hipMemsetAsync(bar,  0, 64, stream);

    pack_w<<<(NG * KTOT) / 256, 256, 0, stream>>>(Wih, Whh, Whi, Wlo);
    pack_x<<<(B_ * S_ * F_) / 256, 256, 0, stream>>>(x, xhi, xlo);

    float* hlast = out + (size_t)B_ * S_ * H_;
    void* args[] = { &xhi, &xlo, &Whi, &Wlo, &bias, &hf,
                     &hhi0, &hlo0, &hhi1, &hlo1, &out, &hlast, &bar };
    hipLaunchCooperativeKernel((void*)gru_persist, dim3(NWG), dim3(NTHR),
                               args, SMEM_BYTES, stream);
}

// Round 4
// 14135.857 us; speedup vs baseline: 3.3227x; 3.3227x over previous
//
#include <hip/hip_runtime.h>
#include <math.h>

// CustomGRU B=64,S=512,F=512,H=1024. FP32 I/O, split-bf16 (hi+lo) MFMA compute.
// Round 3: persistent cooperative kernel, FENCE-FREE step synchronization.
//   - h state: u32-packed (hi_bf16<<16 | lo_bf16), exchanged via agent-scope
//     RELAXED atomic store/load (coherent at LLC; no L2 wb/inv anywhere).
//   - barrier: relaxed atomic ticket + explicit s_waitcnt vmcnt(0) drain.
//     Round 2's __threadfence()/acquire emitted per-step L2 writeback walks
//     (~90us/step, WRITE_SIZE 4.3GB) - all removed.
//   - weights LDS-resident per wg (16 packed rows x K=1536, hi+lo, RS=1544).
//   - Cp reduction tile stride 260 (was 256): 16-way bank conflict -> 4-way.

#define B_   64
#define S_   512
#define F_   512
#define H_   1024
#define KTOT 1536
#define NG   4096
#define NWG  256
#define NTHR 512
#define KCH  192              // K per wave
#define RS   1544             // padded LDS row stride (shorts)
#define CPS  260              // Cp tile stride (floats), pads 16-way -> 4-way
#define SMEM_BYTES (2 * 16 * RS * 2 + 32 * CPS * 4)   // 98816 + 33280 = 132096

typedef short short8 __attribute__((ext_vector_type(8)));
typedef float floatx4 __attribute__((ext_vector_type(4)));

__device__ __forceinline__ float bf2f(unsigned short u) {
    union { unsigned int i; float f; } v; v.i = ((unsigned int)u) << 16; return v.f;
}
__device__ __forceinline__ unsigned short f2bf(float f) {
    union { float f; unsigned int i; } v; v.f = f;
    unsigned int x = v.i;
    x += 0x7fffu + ((x >> 16) & 1u);
    return (unsigned short)(x >> 16);
}
__device__ __forceinline__ void split2(float v, unsigned short& hi, unsigned short& lo) {
    hi = f2bf(v);
    lo = f2bf(v - bf2f(hi));
}

__global__ void pack_w(const float* __restrict__ Wih,
                       const float* __restrict__ Whh,
                       unsigned short* __restrict__ Whi,
                       unsigned short* __restrict__ Wlo) {
    int idx = blockIdx.x * 256 + threadIdx.x;   // < NG*KTOT
    int p = idx / KTOT;
    int k = idx - p * KTOT;
    int j = p >> 2, g = p & 3;
    float v = 0.f;
    if (g == 0)      v = (k < F_) ? Wih[k * 3072 + j]        : Whh[(k - F_) * 3072 + j];
    else if (g == 1) v = (k < F_) ? Wih[k * 3072 + 1024 + j] : Whh[(k - F_) * 3072 + 1024 + j];
    else if (g == 2) { if (k <  F_) v = Wih[k * 3072 + 2048 + j]; }
    else             { if (k >= F_) v = Whh[(k - F_) * 3072 + 2048 + j]; }
    unsigned short hi, lo; split2(v, hi, lo);
    Whi[idx] = hi; Wlo[idx] = lo;
}

__global__ void pack_x(const float* __restrict__ x,
                       unsigned short* __restrict__ xhi,
                       unsigned short* __restrict__ xlo) {
    int idx = blockIdx.x * 256 + threadIdx.x;   // < B_*S_*F_
    unsigned short hi, lo; split2(x[idx], hi, lo);
    xhi[idx] = hi; xlo[idx] = lo;
}

// x-side K step: plain cacheable hi/lo loads
__device__ __forceinline__ void ks_step_x(floatx4* acc,
    const unsigned short* __restrict__ Ahi, const unsigned short* __restrict__ Alo,
    size_t aofs, const unsigned short* Bh_, const unsigned short* Bl_, int bofs)
{
    short8 bh = *(const short8*)&Bh_[bofs];
    short8 bl = *(const short8*)&Bl_[bofs];
    #pragma unroll
    for (int mt = 0; mt < 4; ++mt) {
        size_t o = aofs + (size_t)mt * ((size_t)16 * S_ * F_);
        short8 ah = *(const short8*)&Ahi[o];
        short8 al = *(const short8*)&Alo[o];
        acc[mt] = __builtin_amdgcn_mfma_f32_16x16x32_bf16(ah, bh, acc[mt], 0, 0, 0);
        acc[mt] = __builtin_amdgcn_mfma_f32_16x16x32_bf16(ah, bl, acc[mt], 0, 0, 0);
        acc[mt] = __builtin_amdgcn_mfma_f32_16x16x32_bf16(al, bh, acc[mt], 0, 0, 0);
    }
}

// h-side K step: u32-packed h via agent-scope relaxed atomic u64 loads (LLC)
__device__ __forceinline__ void ks_step_h(floatx4* acc,
    const unsigned* __restrict__ Hp, size_t aofs,
    const unsigned short* Bh_, const unsigned short* Bl_, int bofs)
{
    short8 bh = *(const short8*)&Bh_[bofs];
    short8 bl = *(const short8*)&Bl_[bofs];
    #pragma unroll
    for (int mt = 0; mt < 4; ++mt) {
        const unsigned* p = Hp + aofs + (size_t)mt * (16 * H_);
        short8 ah, al;
        #pragma unroll
        for (int q = 0; q < 4; ++q) {
            unsigned long long d = __hip_atomic_load(
                (const unsigned long long*)p + q,
                __ATOMIC_RELAXED, __HIP_MEMORY_SCOPE_AGENT);
            unsigned w0 = (unsigned)d, w1 = (unsigned)(d >> 32);
            ah[2 * q]     = (short)(w0 >> 16);
            al[2 * q]     = (short)(w0 & 0xffffu);
            ah[2 * q + 1] = (short)(w1 >> 16);
            al[2 * q + 1] = (short)(w1 & 0xffffu);
        }
        acc[mt] = __builtin_amdgcn_mfma_f32_16x16x32_bf16(ah, bh, acc[mt], 0, 0, 0);
        acc[mt] = __builtin_amdgcn_mfma_f32_16x16x32_bf16(ah, bl, acc[mt], 0, 0, 0);
        acc[mt] = __builtin_amdgcn_mfma_f32_16x16x32_bf16(al, bh, acc[mt], 0, 0, 0);
    }
}

__global__ __launch_bounds__(NTHR) void gru_persist(
    const unsigned short* __restrict__ xhi,
    const unsigned short* __restrict__ xlo,
    const unsigned short* __restrict__ Whi,
    const unsigned short* __restrict__ Wlo,
    const float* __restrict__ bias,
    float* __restrict__ hf,
    unsigned* hpk0, unsigned* hpk1,
    float* __restrict__ out,
    float* __restrict__ hlast,
    unsigned* bar)
{
    extern __shared__ char smem[];
    unsigned short* Bh = (unsigned short*)smem;                 // 16 x RS shorts
    unsigned short* Bl = Bh + 16 * RS;
    float* Cp = (float*)(smem + 2 * 16 * RS * 2);               // 32 tiles x CPS f32

    const int tid = threadIdx.x;
    const int wg  = blockIdx.x;

    // ---- stage this wg's weight slice into LDS (once) ----
    for (int c = tid; c < 16 * 192; c += NTHR) {
        int row = c / 192, c8 = c - row * 192;
        size_t gofs = (size_t)(wg * 16 + row) * KTOT + c8 * 8;
        *(short8*)&Bh[row * RS + c8 * 8] = *(const short8*)&Whi[gofs];
        *(short8*)&Bl[row * RS + c8 * 8] = *(const short8*)&Wlo[gofs];
    }
    __syncthreads();

    const int lane = tid & 63;
    const int kw   = tid >> 6;                 // wave id 0..7 -> K chunk
    const int l15  = lane & 15, quad = lane >> 4;
    const int kbase = kw * KCH;
    const int bofs  = l15 * RS + kbase + quad * 8;

    // epilogue constants (threads 0..255: one (batch, col) pair each)
    const int eb   = tid & 63;
    const int ejj  = (tid >> 6) & 3;
    const int ecol = wg * 4 + ejj;
    float bZ = 0.f, bR = 0.f, bE = 0.f;
    if (tid < 256) {
        bZ = bias[ecol];
        bR = bias[H_ + ecol];
        bE = bias[2 * H_ + ecol];
    }
    const int emt = eb >> 4, erow = eb & 15;
    const int elb = (erow >> 2) * 16, err = erow & 3;
    const int ehidx = eb * H_ + ecol;

    const size_t hrow = (size_t)l15 * H_ + quad * 8;  // u32 index into hpk

    for (int t = 0; t < S_; ++t) {
        const unsigned* hin = (t & 1) ? hpk1 : hpk0;
        unsigned*      hout = (t & 1) ? hpk0 : hpk1;

        floatx4 z4 = {0.f, 0.f, 0.f, 0.f};
        floatx4 acc[4] = {z4, z4, z4, z4};

        const size_t xrow = ((size_t)l15 * S_ + t) * F_ + quad * 8;

        if (kbase + KCH <= 512) {              // waves 0,1: pure x
            #pragma unroll
            for (int ks = 0; ks < 6; ++ks)
                ks_step_x(acc, xhi, xlo, xrow + kbase + ks * 32, Bh, Bl, bofs + ks * 32);
        } else if (kbase >= 512) {             // waves 3..7: pure h
            #pragma unroll
            for (int ks = 0; ks < 6; ++ks)
                ks_step_h(acc, hin, hrow + (kbase - 512) + ks * 32, Bh, Bl, bofs + ks * 32);
        } else {                               // wave 2: 4 x-steps + 2 h-steps
            #pragma unroll
            for (int ks = 0; ks < 4; ++ks)
                ks_step_x(acc, xhi, xlo, xrow + kbase + ks * 32, Bh, Bl, bofs + ks * 32);
            #pragma unroll
            for (int ks = 4; ks < 6; ++ks)
                ks_step_h(acc, hin, hrow + (kbase - 512) + ks * 32, Bh, Bl, bofs + ks * 32);
        }

        #pragma unroll
        for (int mt = 0; mt < 4; ++mt)
            *(floatx4*)&Cp[(kw * 4 + mt) * CPS + lane * 4] = acc[mt];
        __syncthreads();

        if (tid < 256) {
            float g[4];
            #pragma unroll
            for (int gi = 0; gi < 4; ++gi) {
                const int c = ejj * 4 + gi;
                const int base = (elb + c) * 4 + err;
                float s = 0.f;
                #pragma unroll
                for (int k2 = 0; k2 < 8; ++k2)
                    s += Cp[(k2 * 4 + emt) * CPS + base];
                g[gi] = s;
            }
            float z   = 1.f / (1.f + __expf(-(g[0] + bZ)));
            float rr  = 1.f / (1.f + __expf(-(g[1] + bR)));
            float eta = tanhf(g[2] + bE + rr * tanhf(g[3]));
            float ho  = hf[ehidx];
            float hn  = z * ho + (1.f - z) * eta;
            hf[ehidx] = hn;
            unsigned short hi, lo; split2(hn, hi, lo);
            unsigned pk = ((unsigned)hi << 16) | (unsigned)lo;
            __hip_atomic_store(&hout[ehidx], pk,
                               __ATOMIC_RELAXED, __HIP_MEMORY_SCOPE_AGENT);
            out[((size_t)eb * S_ + t) * H_ + ecol] = hn;
            if (t == S_ - 1) hlast[ehidx] = hn;
        }

        // ---- fence-free grid barrier (relaxed ticket + explicit drain) ----
        __asm__ volatile("s_waitcnt vmcnt(0)" ::: "memory");  // h stores at LLC
        __syncthreads();
        if (tid == 0) {
            __hip_atomic_fetch_add(bar, 1u, __ATOMIC_RELAXED, __HIP_MEMORY_SCOPE_AGENT);
            const unsigned target = (unsigned)(t + 1) * NWG;
            while (__hip_atomic_load(bar, __ATOMIC_RELAXED, __HIP_MEMORY_SCOPE_AGENT) < target)
                __builtin_amdgcn_s_sleep(2);
        }
        __syncthreads();
    }
}

extern "C" void kernel_launch(void* const* d_in, const int* in_sizes, int n_in,
                              void* d_out, int out_size, void* d_ws, size_t ws_size,
                              hipStream_t stream) {
    const float* x    = (const float*)d_in[0];   // [B,S,F]
    const float* Wih  = (const float*)d_in[1];   // [F,3H]
    const float* Whh  = (const float*)d_in[2];   // [H,3H]
    const float* bias = (const float*)d_in[3];   // [3H]
    float* out = (float*)d_out;                  // [B,S,H] ++ [B,H]

    char* ws = (char*)d_ws;
    unsigned short* Whi = (unsigned short*)ws; ws += (size_t)NG * KTOT * 2;
    unsigned short* Wlo = (unsigned short*)ws; ws += (size_t)NG * KTOT * 2;
    unsigned short* xhi = (unsigned short*)ws; ws += (size_t)B_ * S_ * F_ * 2;
    unsigned short* xlo = (unsigned short*)ws; ws += (size_t)B_ * S_ * F_ * 2;
    float* hf = (float*)ws;                    ws += (size_t)B_ * H_ * 4;
    unsigned* hpk0 = (unsigned*)ws;            ws += (size_t)B_ * H_ * 4;
    unsigned* hpk1 = (unsigned*)ws;            ws += (size_t)B_ * H_ * 4;
    unsigned* bar = (unsigned*)ws;             ws += 64;

    hipMemsetAsync(hf,   0, (size_t)B_ * H_ * 4, stream);
    hipMemsetAsync(hpk0, 0, (size_t)B_ * H_ * 4, stream);
    hipMemsetAsync(bar,  0, 64, stream);

    pack_w<<<(NG * KTOT) / 256, 256, 0, stream>>>(Wih, Whh, Whi, Wlo);
    pack_x<<<(B_ * S_ * F_) / 256, 256, 0, stream>>>(x, xhi, xlo);

    float* hlast = out + (size_t)B_ * S_ * H_;
    void* args[] = { &xhi, &xlo, &Whi, &Wlo, &bias, &hf,
                     &hpk0, &hpk1, &out, &hlast, &bar };
    hipLaunchCooperativeKernel((void*)gru_persist, dim3(NWG), dim3(NTHR),
                               args, SMEM_BYTES, stream);
}

// Round 5
// 12148.532 us; speedup vs baseline: 3.8662x; 1.1636x over previous
//
#include <hip/hip_runtime.h>
#include <math.h>

// CustomGRU B=64,S=512,F=512,H=1024. FP32 I/O, split-bf16 (hi+lo) MFMA compute.
// Round 5: persistent cooperative kernel; h exchanged via BATCHED device-scope
// (sc0 sc1) loads/stores written in inline asm (8 dwordx4 in flight, one
// waitcnt) instead of per-element relaxed atomics, which LLVM serialized at
// ~700cyc each (round 4: 66k cyc/step, 96% idle). h kept as separate hi/lo
// bf16 arrays so fragments load directly as short8 (no unpack VALU).
// Uniform wave split: every wave = 2 x-ksteps (L2) + 4 h-ksteps (LLC).

#define B_   64
#define S_   512
#define F_   512
#define H_   1024
#define KTOT 1536
#define NG   4096
#define NWG  256
#define NTHR 512
#define RS   1544             // padded LDS row stride (shorts)
#define CPS  260              // Cp tile stride (floats): 16-way conflict -> 4-way
#define SMEM_BYTES (2 * 16 * RS * 2 + 32 * CPS * 4)   // 98816 + 33280 = 132096

typedef short short8 __attribute__((ext_vector_type(8)));
typedef float floatx4 __attribute__((ext_vector_type(4)));

__device__ __forceinline__ float bf2f(unsigned short u) {
    union { unsigned int i; float f; } v; v.i = ((unsigned int)u) << 16; return v.f;
}
__device__ __forceinline__ unsigned short f2bf(float f) {
    union { float f; unsigned int i; } v; v.f = f;
    unsigned int x = v.i;
    x += 0x7fffu + ((x >> 16) & 1u);
    return (unsigned short)(x >> 16);
}
__device__ __forceinline__ void split2(float v, unsigned short& hi, unsigned short& lo) {
    hi = f2bf(v);
    lo = f2bf(v - bf2f(hi));
}

__global__ void pack_w(const float* __restrict__ Wih,
                       const float* __restrict__ Whh,
                       unsigned short* __restrict__ Whi,
                       unsigned short* __restrict__ Wlo) {
    int idx = blockIdx.x * 256 + threadIdx.x;   // < NG*KTOT
    int p = idx / KTOT;
    int k = idx - p * KTOT;
    int j = p >> 2, g = p & 3;
    float v = 0.f;
    if (g == 0)      v = (k < F_) ? Wih[k * 3072 + j]        : Whh[(k - F_) * 3072 + j];
    else if (g == 1) v = (k < F_) ? Wih[k * 3072 + 1024 + j] : Whh[(k - F_) * 3072 + 1024 + j];
    else if (g == 2) { if (k <  F_) v = Wih[k * 3072 + 2048 + j]; }
    else             { if (k >= F_) v = Whh[(k - F_) * 3072 + 2048 + j]; }
    unsigned short hi, lo; split2(v, hi, lo);
    Whi[idx] = hi; Wlo[idx] = lo;
}

__global__ void pack_x(const float* __restrict__ x,
                       unsigned short* __restrict__ xhi,
                       unsigned short* __restrict__ xlo) {
    int idx = blockIdx.x * 256 + threadIdx.x;   // < B_*S_*F_
    unsigned short hi, lo; split2(x[idx], hi, lo);
    xhi[idx] = hi; xlo[idx] = lo;
}

// x-side K step: plain cacheable (L1/L2) hi/lo loads
__device__ __forceinline__ void ks_step_x(floatx4* acc,
    const unsigned short* __restrict__ Ahi, const unsigned short* __restrict__ Alo,
    size_t aofs, const unsigned short* Bh_, const unsigned short* Bl_, int bofs)
{
    short8 bh = *(const short8*)&Bh_[bofs];
    short8 bl = *(const short8*)&Bl_[bofs];
    #pragma unroll
    for (int mt = 0; mt < 4; ++mt) {
        size_t o = aofs + (size_t)mt * ((size_t)16 * S_ * F_);
        short8 ah = *(const short8*)&Ahi[o];
        short8 al = *(const short8*)&Alo[o];
        acc[mt] = __builtin_amdgcn_mfma_f32_16x16x32_bf16(ah, bh, acc[mt], 0, 0, 0);
        acc[mt] = __builtin_amdgcn_mfma_f32_16x16x32_bf16(ah, bl, acc[mt], 0, 0, 0);
        acc[mt] = __builtin_amdgcn_mfma_f32_16x16x32_bf16(al, bh, acc[mt], 0, 0, 0);
    }
}

// h-side K step: 8 device-scope (LLC) loads in flight, single waitcnt.
__device__ __forceinline__ void ks_step_h(floatx4* acc,
    const unsigned short* Hhi, const unsigned short* Hlo, size_t aofs,
    const unsigned short* Bh_, const unsigned short* Bl_, int bofs)
{
    short8 bh = *(const short8*)&Bh_[bofs];
    short8 bl = *(const short8*)&Bl_[bofs];
    const unsigned short* ph0 = Hhi + aofs;
    const unsigned short* pl0 = Hlo + aofs;
    short8 ah0, al0, ah1, al1, ah2, al2, ah3, al3;
    asm volatile(
        "global_load_dwordx4 %0, %[h0], off sc0 sc1\n\t"
        "global_load_dwordx4 %1, %[l0], off sc0 sc1\n\t"
        "global_load_dwordx4 %2, %[h1], off sc0 sc1\n\t"
        "global_load_dwordx4 %3, %[l1], off sc0 sc1\n\t"
        "global_load_dwordx4 %4, %[h2], off sc0 sc1\n\t"
        "global_load_dwordx4 %5, %[l2], off sc0 sc1\n\t"
        "global_load_dwordx4 %6, %[h3], off sc0 sc1\n\t"
        "global_load_dwordx4 %7, %[l3], off sc0 sc1\n\t"
        "s_waitcnt vmcnt(0)"
        : "=&v"(ah0), "=&v"(al0), "=&v"(ah1), "=&v"(al1),
          "=&v"(ah2), "=&v"(al2), "=&v"(ah3), "=&v"(al3)
        : [h0]"v"(ph0),             [l0]"v"(pl0),
          [h1]"v"(ph0 + 16 * H_),   [l1]"v"(pl0 + 16 * H_),
          [h2]"v"(ph0 + 32 * H_),   [l2]"v"(pl0 + 32 * H_),
          [h3]"v"(ph0 + 48 * H_),   [l3]"v"(pl0 + 48 * H_)
        : "memory");
    acc[0] = __builtin_amdgcn_mfma_f32_16x16x32_bf16(ah0, bh, acc[0], 0, 0, 0);
    acc[0] = __builtin_amdgcn_mfma_f32_16x16x32_bf16(ah0, bl, acc[0], 0, 0, 0);
    acc[0] = __builtin_amdgcn_mfma_f32_16x16x32_bf16(al0, bh, acc[0], 0, 0, 0);
    acc[1] = __builtin_amdgcn_mfma_f32_16x16x32_bf16(ah1, bh, acc[1], 0, 0, 0);
    acc[1] = __builtin_amdgcn_mfma_f32_16x16x32_bf16(ah1, bl, acc[1], 0, 0, 0);
    acc[1] = __builtin_amdgcn_mfma_f32_16x16x32_bf16(al1, bh, acc[1], 0, 0, 0);
    acc[2] = __builtin_amdgcn_mfma_f32_16x16x32_bf16(ah2, bh, acc[2], 0, 0, 0);
    acc[2] = __builtin_amdgcn_mfma_f32_16x16x32_bf16(ah2, bl, acc[2], 0, 0, 0);
    acc[2] = __builtin_amdgcn_mfma_f32_16x16x32_bf16(al2, bh, acc[2], 0, 0, 0);
    acc[3] = __builtin_amdgcn_mfma_f32_16x16x32_bf16(ah3, bh, acc[3], 0, 0, 0);
    acc[3] = __builtin_amdgcn_mfma_f32_16x16x32_bf16(ah3, bl, acc[3], 0, 0, 0);
    acc[3] = __builtin_amdgcn_mfma_f32_16x16x32_bf16(al3, bh, acc[3], 0, 0, 0);
}

__global__ __launch_bounds__(NTHR) void gru_persist(
    const unsigned short* __restrict__ xhi,
    const unsigned short* __restrict__ xlo,
    const unsigned short* __restrict__ Whi,
    const unsigned short* __restrict__ Wlo,
    const float* __restrict__ bias,
    float* __restrict__ hf,
    unsigned short* hhi0, unsigned short* hlo0,
    unsigned short* hhi1, unsigned short* hlo1,
    float* __restrict__ out,
    float* __restrict__ hlast,
    unsigned* bar)
{
    extern __shared__ char smem[];
    unsigned short* Bh = (unsigned short*)smem;                 // 16 x RS shorts
    unsigned short* Bl = Bh + 16 * RS;
    float* Cp = (float*)(smem + 2 * 16 * RS * 2);               // 32 tiles x CPS f32

    const int tid = threadIdx.x;
    const int wg  = blockIdx.x;

    // ---- stage this wg's weight slice into LDS (once) ----
    for (int c = tid; c < 16 * 192; c += NTHR) {
        int row = c / 192, c8 = c - row * 192;
        size_t gofs = (size_t)(wg * 16 + row) * KTOT + c8 * 8;
        *(short8*)&Bh[row * RS + c8 * 8] = *(const short8*)&Whi[gofs];
        *(short8*)&Bl[row * RS + c8 * 8] = *(const short8*)&Wlo[gofs];
    }
    __syncthreads();

    const int lane = tid & 63;
    const int kw   = tid >> 6;                 // wave id 0..7
    const int l15  = lane & 15, quad = lane >> 4;
    // uniform split: wave kw covers x-K [kw*64, kw*64+64) and h-K [kw*128, +128)
    const int xk0   = kw * 64;
    const int hk0   = kw * 128;
    const int bofsx = l15 * RS + xk0 + quad * 8;
    const int bofsh = l15 * RS + 512 + hk0 + quad * 8;

    // epilogue constants (threads 0..255: one (batch, col) pair each)
    const int eb   = tid & 63;
    const int ejj  = (tid >> 6) & 3;
    const int ecol = wg * 4 + ejj;
    float bZ = 0.f, bR = 0.f, bE = 0.f;
    if (tid < 256) {
        bZ = bias[ecol];
        bR = bias[H_ + ecol];
        bE = bias[2 * H_ + ecol];
    }
    const int emt = eb >> 4, erow = eb & 15;
    const int elb = (erow >> 2) * 16, err = erow & 3;
    const int ehidx = eb * H_ + ecol;

    const size_t hrow = (size_t)l15 * H_ + quad * 8;

    for (int t = 0; t < S_; ++t) {
        const unsigned short* hih = (t & 1) ? hhi1 : hhi0;
        const unsigned short* hil = (t & 1) ? hlo1 : hlo0;
        unsigned short* hoh = (t & 1) ? hhi0 : hhi1;
        unsigned short* hol = (t & 1) ? hlo0 : hlo1;

        floatx4 z4 = {0.f, 0.f, 0.f, 0.f};
        floatx4 acc[4] = {z4, z4, z4, z4};

        const size_t xrow = ((size_t)l15 * S_ + t) * F_ + quad * 8;

        #pragma unroll
        for (int ks = 0; ks < 2; ++ks)
            ks_step_x(acc, xhi, xlo, xrow + xk0 + ks * 32, Bh, Bl, bofsx + ks * 32);
        #pragma unroll
        for (int ks = 0; ks < 4; ++ks)
            ks_step_h(acc, hih, hil, hrow + hk0 + ks * 32, Bh, Bl, bofsh + ks * 32);

        #pragma unroll
        for (int mt = 0; mt < 4; ++mt)
            *(floatx4*)&Cp[(kw * 4 + mt) * CPS + lane * 4] = acc[mt];
        __syncthreads();

        if (tid < 256) {
            float g[4];
            #pragma unroll
            for (int gi = 0; gi < 4; ++gi) {
                const int c = ejj * 4 + gi;
                const int base = (elb + c) * 4 + err;
                float s = 0.f;
                #pragma unroll
                for (int k2 = 0; k2 < 8; ++k2)
                    s += Cp[(k2 * 4 + emt) * CPS + base];
                g[gi] = s;
            }
            float z   = 1.f / (1.f + __expf(-(g[0] + bZ)));
            float rr  = 1.f / (1.f + __expf(-(g[1] + bR)));
            float eta = tanhf(g[2] + bE + rr * tanhf(g[3]));
            float ho  = hf[ehidx];
            float hn  = z * ho + (1.f - z) * eta;
            hf[ehidx] = hn;
            unsigned short hi, lo; split2(hn, hi, lo);
            asm volatile("global_store_short %0, %1, off sc0 sc1"
                         :: "v"(&hoh[ehidx]), "v"((unsigned)hi) : "memory");
            asm volatile("global_store_short %0, %1, off sc0 sc1"
                         :: "v"(&hol[ehidx]), "v"((unsigned)lo) : "memory");
            out[((size_t)eb * S_ + t) * H_ + ecol] = hn;
            if (t == S_ - 1) hlast[ehidx] = hn;
        }

        // ---- fence-free grid barrier (relaxed ticket + explicit drain) ----
        __asm__ volatile("s_waitcnt vmcnt(0)" ::: "memory");  // h stores at LLC
        __syncthreads();
        if (tid == 0) {
            __hip_atomic_fetch_add(bar, 1u, __ATOMIC_RELAXED, __HIP_MEMORY_SCOPE_AGENT);
            const unsigned target = (unsigned)(t + 1) * NWG;
            while (__hip_atomic_load(bar, __ATOMIC_RELAXED, __HIP_MEMORY_SCOPE_AGENT) < target)
                __builtin_amdgcn_s_sleep(2);
        }
        __syncthreads();
    }
}

extern "C" void kernel_launch(void* const* d_in, const int* in_sizes, int n_in,
                              void* d_out, int out_size, void* d_ws, size_t ws_size,
                              hipStream_t stream) {
    const float* x    = (const float*)d_in[0];   // [B,S,F]
    const float* Wih  = (const float*)d_in[1];   // [F,3H]
    const float* Whh  = (const float*)d_in[2];   // [H,3H]
    const float* bias = (const float*)d_in[3];   // [3H]
    float* out = (float*)d_out;                  // [B,S,H] ++ [B,H]

    char* ws = (char*)d_ws;
    unsigned short* Whi = (unsigned short*)ws; ws += (size_t)NG * KTOT * 2;
    unsigned short* Wlo = (unsigned short*)ws; ws += (size_t)NG * KTOT * 2;
    unsigned short* xhi = (unsigned short*)ws; ws += (size_t)B_ * S_ * F_ * 2;
    unsigned short* xlo = (unsigned short*)ws; ws += (size_t)B_ * S_ * F_ * 2;
    float* hf = (float*)ws;                    ws += (size_t)B_ * H_ * 4;
    unsigned short* hhi0 = (unsigned short*)ws; ws += (size_t)B_ * H_ * 2;
    unsigned short* hlo0 = (unsigned short*)ws; ws += (size_t)B_ * H_ * 2;
    unsigned short* hhi1 = (unsigned short*)ws; ws += (size_t)B_ * H_ * 2;
    unsigned short* hlo1 = (unsigned short*)ws; ws += (size_t)B_ * H_ * 2;
    unsigned* bar = (unsigned*)ws;             ws += 64;

    hipMemsetAsync(hf,   0, (size_t)B_ * H_ * 4, stream);
    hipMemsetAsync(hhi0, 0, (size_t)B_ * H_ * 2, stream);
    hipMemsetAsync(hlo0, 0, (size_t)B_ * H_ * 2, stream);
    hipMemsetAsync(bar,  0, 64, stream);

    pack_w<<<(NG * KTOT) / 256, 256, 0, stream>>>(Wih, Whh, Whi, Wlo);
    pack_x<<<(B_ * S_ * F_) / 256, 256, 0, stream>>>(x, xhi, xlo);

    float* hlast = out + (size_t)B_ * S_ * H_;
    void* args[] = { &xhi, &xlo, &Whi, &Wlo, &bias, &hf,
                     &hhi0, &hlo0, &hhi1, &hlo1, &out, &hlast, &bar };
    hipLaunchCooperativeKernel((void*)gru_persist, dim3(NWG), dim3(NTHR),
                               args, SMEM_BYTES, stream);
}